// Round 5
// baseline (12769.170 us; speedup 1.0000x reference)
//
#include <hip/hip_runtime.h>

#define FPS_N 32768
#define FPS_M 2048
#define FPS_B 16
#define FPS_T 512
#define NPAIR (FPS_N / 2)      // 16384 float2 pairs
#define KPT (NPAIR / FPS_T)    // 32 pairs per thread (64 points)
#define NWAVE (FPS_T / 64)     // 8 waves

typedef float vf2 __attribute__((ext_vector_type(2)));

// One block per batch (algorithm sequential in m -> 16 CUs active).
// REGISTER RESIDENCY, attempt 4 (decisive):
//  - Rounds 2/4 evidence: allocator grants HALF the occupancy-permitted arch
//    VGPRs on gfx950 (unified VGPR/AGPR file 50/50 split): got 64@cap128,
//    128@cap256. Remaining ~94 regs spilled to scratch -> ~190 KB/block/step
//    reload stream (= the GB-scale FETCH_SIZE, 12.6 ms).
//  - Fix A: amdgpu_waves_per_eu(1) -> per-wave budget 512, half = 256 arch
//    VGPRs. HW still runs all 8 waves (8x256 = 2048 = full CU file); real
//    occupancy is LDS-bound at 1 wg/CU regardless, so the attr only raises
//    the allocator budget.
//  - Fix B: asm volatile "+v" pin on each coord reg: inline-asm results
//    cannot be rematerialized/sunk -- RA must keep them live.
// Coords: 192 VGPRs register-resident. Dist: 128 KiB LDS, ds_read_b64 +
// conditional write (sparse after warmup -> s_cbranch_execz skips it).
// Argmax: 4 independent chains, merged with explicit lowest-index tie-break.
// Numerics bit-exact vs numpy: contract off, IEEE pk-f32, sum order
// (dx*dx + dy*dy) + dz*dz, strict-> / first-occurrence argmax.
__global__ __launch_bounds__(FPS_T)
__attribute__((amdgpu_waves_per_eu(1)))
void fps_kernel(const float* __restrict__ pts, float* __restrict__ out) {
#pragma clang fp contract(off)
    __shared__ vf2 sdist[NPAIR];           // 128 KiB
    __shared__ float red_d[2][NWAVE];
    __shared__ int   red_i[2][NWAVE];

    const int b = blockIdx.x;
    const int tid = threadIdx.x;
    const float* __restrict__ X = pts + (size_t)b * 3 * FPS_N;
    const float* __restrict__ Y = X + FPS_N;
    const float* __restrict__ Z = Y + FPS_N;
    const vf2* __restrict__ X2 = (const vf2*)X;
    const vf2* __restrict__ Y2 = (const vf2*)Y;
    const vf2* __restrict__ Z2 = (const vf2*)Z;
    float* __restrict__ outb = out + (size_t)b * 3 * FPS_M;

    vf2 x[KPT], y[KPT], z[KPT];            // 192 VGPRs — must stay resident
#pragma unroll
    for (int k = 0; k < KPT; ++k) {
        const int q = k * FPS_T + tid;     // coalesced 8B loads
        x[k] = X2[q];
        y[k] = Y2[q];
        z[k] = Z2[q];
        sdist[q] = (vf2){1e10f, 1e10f};
    }
    // Pin: values become inline-asm results -> non-rematerializable, RA must
    // allocate them (budget 256 now permits it).
#pragma unroll
    for (int k = 0; k < KPT; ++k) {
        asm volatile("" : "+v"(x[k]), "+v"(y[k]), "+v"(z[k]));
    }
    // first selected index is 0 (CUDA FPS convention)
    float lx = X[0], ly = Y[0], lz = Z[0];
    __syncthreads();

    for (int s = 0; s < FPS_M; ++s) {
        if (tid == 0) {                    // emit selection (gather by index)
            outb[s] = lx;
            outb[FPS_M + s] = ly;
            outb[2 * FPS_M + s] = lz;
        }

        const vf2 lx2 = {lx, lx}, ly2 = {ly, ly}, lz2 = {lz, lz};
        float bd[4] = {-1.0f, -1.0f, -1.0f, -1.0f};
        int   bi[4] = {0, 0, 0, 0};
#pragma unroll
        for (int k = 0; k < KPT; ++k) {
            const int q = k * FPS_T + tid;
            vf2 dx = x[k] - lx2;                       // v_pk_add_f32
            vf2 dy = y[k] - ly2;
            vf2 dz = z[k] - lz2;
            vf2 d = (dx * dx + dy * dy) + dz * dz;     // numpy op order, no fma
            vf2 dv = sdist[q];                         // ds_read_b64
            const bool w0 = d.x < dv.x;
            const bool w1 = d.y < dv.y;
            vf2 nd;
            nd.x = w0 ? d.x : dv.x;                    // min(dist, d)
            nd.y = w1 ? d.y : dv.y;
            if (w0 | w1) sdist[q] = nd;                // sparse write, execz-skipped
            const int c = k & 3;                       // 4 chains break dep chain
            if (nd.x > bd[c]) { bd[c] = nd.x; bi[c] = 2 * q; }
            if (nd.y > bd[c]) { bd[c] = nd.y; bi[c] = 2 * q + 1; }
        }
        // merge chains (explicit tie-break: lowest global index)
        float tbd = bd[0];
        int   tbi = bi[0];
#pragma unroll
        for (int c = 1; c < 4; ++c)
            if (bd[c] > tbd || (bd[c] == tbd && bi[c] < tbi)) { tbd = bd[c]; tbi = bi[c]; }

        // 64-lane wave reduce: max dist, ties -> lowest index
#pragma unroll
        for (int off = 32; off > 0; off >>= 1) {
            float od = __shfl_down(tbd, off);
            int   oi = __shfl_down(tbi, off);
            if (od > tbd || (od == tbd && oi < tbi)) { tbd = od; tbi = oi; }
        }
        const int wave = tid >> 6;
        const int par = s & 1;
        if ((tid & 63) == 0) { red_d[par][wave] = tbd; red_i[par][wave] = tbi; }
        __syncthreads();

        // all threads reduce the 8 wave partials (LDS broadcast reads);
        // parity double-buffer -> no second barrier.
        float wbd = red_d[par][0];
        int   wbi = red_i[par][0];
#pragma unroll
        for (int w = 1; w < NWAVE; ++w) {
            float od = red_d[par][w];
            int   oi = red_i[par][w];
            if (od > wbd || (od == wbd && oi < wbi)) { wbd = od; wbi = oi; }
        }

        // winner coords: wave-uniform address -> one L2 request per wave
        lx = X[wbi];
        ly = Y[wbi];
        lz = Z[wbi];
    }
}

extern "C" void kernel_launch(void* const* d_in, const int* in_sizes, int n_in,
                              void* d_out, int out_size, void* d_ws, size_t ws_size,
                              hipStream_t stream) {
    const float* pts = (const float*)d_in[0];   // [16, 3, 32768] fp32
    float* out = (float*)d_out;                 // [16, 3, 2048] fp32
    hipLaunchKernelGGL(fps_kernel, dim3(FPS_B), dim3(FPS_T), 0, stream, pts, out);
}

// Round 6
// 7817.675 us; speedup vs baseline: 1.6334x; 1.6334x over previous
//
#include <hip/hip_runtime.h>

#define FPS_N 32768
#define FPS_M 2048
#define FPS_B 16
#define BLK_PER_B 8
#define FPS_T 512
#define PTS (FPS_N / BLK_PER_B)   // 4096 points per block
#define PPT (PTS / FPS_T)         // 8 points per thread
#define NWAVE (FPS_T / 64)        // 8 waves

// FPS split 8 ways per batch; 128 blocks total, cooperative launch (guaranteed
// co-residency). Per-point state (16 B x 32768 = 512 KiB/batch) provably cannot
// fit one CU (rounds 1-5: RA grants at most 128 arch VGPRs -> permanent spill,
// 9-17 ms). Split 8x: coords 64 KiB LDS/block (float4 -> ds_read_b128), dist
// 8 VGPRs/thread. Per step, blocks exchange (dist,idx,x,y,z) via agent-scope
// atomics in d_ws: payload carries the winner's coords so there is NO global
// memory in the steady-state loop at all. Slots are parity double-buffered
// (a block may only overwrite a parity slot 2 steps later, by which time all
// peers provably consumed it: publish(s+2) requires reading all s+1 payloads).
// Tag = s+1 in low 16 bits of the release word; ws poison 0xAAAA never matches.
// Numerics bit-exact vs numpy: contract off, sum order (dx*dx+dy*dy)+dz*dz,
// strict > / lowest-global-index ties == np.argmax first occurrence.
__global__ __launch_bounds__(FPS_T) void fps_kernel(const float* __restrict__ pts,
                                                    float* __restrict__ out,
                                                    unsigned long long* __restrict__ ws) {
#pragma clang fp contract(off)
    __shared__ float4 sc[PTS];          // 64 KiB coords
    __shared__ float red_d[NWAVE];
    __shared__ int   red_i[NWAVE];
    __shared__ float swin[3];

    const int blk = blockIdx.x;
    const int b = blk >> 3;             // batch
    const int j = blk & 7;              // block-within-batch
    const int tid = threadIdx.x;
    const float* __restrict__ X = pts + (size_t)b * 3 * FPS_N;
    const float* __restrict__ Y = X + FPS_N;
    const float* __restrict__ Z = Y + FPS_N;
    const int off = j * PTS;
    float* __restrict__ outb = out + (size_t)b * 3 * FPS_M;

    // one-time stage: this block's 4096 coords -> LDS (coalesced global reads)
    for (int q = tid; q < PTS; q += FPS_T)
        sc[q] = make_float4(X[off + q], Y[off + q], Z[off + q], 0.0f);

    float dist[PPT];
#pragma unroll
    for (int k = 0; k < PPT; ++k) dist[k] = 1e10f;

    float lx = X[0], ly = Y[0], lz = Z[0];   // first selection = index 0
    __syncthreads();

    for (int s = 0; s < FPS_M; ++s) {
        if (j == 0 && tid == 0) {            // emit current selection's coords
            outb[s] = lx;
            outb[FPS_M + s] = ly;
            outb[2 * FPS_M + s] = lz;
        }
        if (s == FPS_M - 1) break;           // last scan is unused by the output

        // scan own points: dist update (regs) + local argmax
        float bd = -1.0f;
        int bi = 0;
#pragma unroll
        for (int k = 0; k < PPT; ++k) {
            const int q = k * FPS_T + tid;
            float4 c = sc[q];                            // ds_read_b128
            float dx = c.x - lx, dy = c.y - ly, dz = c.z - lz;
            float d = (dx * dx + dy * dy) + dz * dz;     // numpy op order, no fma
            float nd = d < dist[k] ? d : dist[k];
            dist[k] = nd;
            if (nd > bd) { bd = nd; bi = q; }            // strict >: lowest idx
        }

        // 64-lane wave reduce (ascending-index ties -> lowest local idx)
#pragma unroll
        for (int o = 32; o > 0; o >>= 1) {
            float od = __shfl_down(bd, o);
            int   oi = __shfl_down(bi, o);
            if (od > bd || (od == bd && oi < bi)) { bd = od; bi = oi; }
        }
        if ((tid & 63) == 0) { red_d[tid >> 6] = bd; red_i[tid >> 6] = bi; }
        __syncthreads();

        if (tid < 64) {                      // wave 0 handles exchange
            // cross-wave reduce (8 partials in lanes 0-7)
            float d8 = (tid < NWAVE) ? red_d[tid] : -1.0f;
            int   i8 = (tid < NWAVE) ? red_i[tid] : 0x7fffffff;
#pragma unroll
            for (int o = 4; o > 0; o >>= 1) {
                float od = __shfl_down(d8, o);
                int   oi = __shfl_down(i8, o);
                if (od > d8 || (od == d8 && oi < i8)) { d8 = od; i8 = oi; }
            }
            // lane 0 publishes (d, global idx, x, y, z, tag) to own parity slot
            const int par = s & 1;
            if (tid == 0) {
                float4 c = sc[i8];
                const unsigned g = (unsigned)(off + i8);     // batch-global idx <32768
                unsigned long long* slot = ws + (size_t)(b * 8 + j) * 16 + par * 4;
                unsigned long long w0 = ((unsigned long long)__float_as_uint(c.y) << 32)
                                        | __float_as_uint(c.x);
                unsigned long long w1 = (unsigned long long)__float_as_uint(c.z);
                unsigned long long w2 = ((unsigned long long)__float_as_uint(d8) << 32)
                                        | (g << 16) | (unsigned)(s + 1);
                __hip_atomic_store(slot + 0, w0, __ATOMIC_RELAXED, __HIP_MEMORY_SCOPE_AGENT);
                __hip_atomic_store(slot + 1, w1, __ATOMIC_RELAXED, __HIP_MEMORY_SCOPE_AGENT);
                __hip_atomic_store(slot + 2, w2, __ATOMIC_RELEASE, __HIP_MEMORY_SCOPE_AGENT);
            }
            // lanes 0-7 poll the batch's 8 slots for tag == s+1
            unsigned long long* pslot = ws + (size_t)(b * 8 + (tid & 7)) * 16 + par * 4;
            unsigned long long w2v = 0;
            bool ok = (tid >= 8);
            for (int it = 0; it < (1 << 27); ++it) {
                if (!ok) {
                    w2v = __hip_atomic_load(pslot + 2, __ATOMIC_ACQUIRE,
                                            __HIP_MEMORY_SCOPE_AGENT);
                    ok = ((unsigned)(w2v & 0xFFFFu) == (unsigned)(s + 1));
                }
                if (__all(ok)) break;
                __builtin_amdgcn_s_sleep(2);
            }
            // extract payloads (acquire on w2 orders these loads)
            float pd, px, py, pz;
            int pidx;
            if (tid < 8) {
                unsigned long long w0 = __hip_atomic_load(pslot + 0, __ATOMIC_RELAXED,
                                                          __HIP_MEMORY_SCOPE_AGENT);
                unsigned long long w1 = __hip_atomic_load(pslot + 1, __ATOMIC_RELAXED,
                                                          __HIP_MEMORY_SCOPE_AGENT);
                pd   = __uint_as_float((unsigned)(w2v >> 32));
                pidx = (int)((w2v >> 16) & 0xFFFFu);
                px   = __uint_as_float((unsigned)(w0 & 0xFFFFFFFFu));
                py   = __uint_as_float((unsigned)(w0 >> 32));
                pz   = __uint_as_float((unsigned)(w1 & 0xFFFFFFFFu));
            } else { pd = -1.0f; pidx = 0x7fffffff; px = py = pz = 0.0f; }
            // reduce 8 block partials: max dist, ties -> lowest GLOBAL index
#pragma unroll
            for (int o = 4; o > 0; o >>= 1) {
                float od = __shfl_down(pd, o);
                int   oi = __shfl_down(pidx, o);
                float ox = __shfl_down(px, o);
                float oy = __shfl_down(py, o);
                float oz = __shfl_down(pz, o);
                if (od > pd || (od == pd && oi < pidx)) {
                    pd = od; pidx = oi; px = ox; py = oy; pz = oz;
                }
            }
            if (tid == 0) { swin[0] = px; swin[1] = py; swin[2] = pz; }
        }
        __syncthreads();
        lx = swin[0];
        ly = swin[1];
        lz = swin[2];
    }
}

extern "C" void kernel_launch(void* const* d_in, const int* in_sizes, int n_in,
                              void* d_out, int out_size, void* d_ws, size_t ws_size,
                              hipStream_t stream) {
    const float* pts = (const float*)d_in[0];          // [16, 3, 32768] fp32
    float* out = (float*)d_out;                        // [16, 3, 2048] fp32
    unsigned long long* ws = (unsigned long long*)d_ws; // 16*8*128 B = 16 KB used
    void* args[] = { (void*)&pts, (void*)&out, (void*)&ws };
    hipLaunchCooperativeKernel((const void*)fps_kernel,
                               dim3(FPS_B * BLK_PER_B), dim3(FPS_T),
                               args, 0, stream);
}